// Round 2
// baseline (1132.414 us; speedup 1.0000x reference)
//
#include <hip/hip_runtime.h>

typedef _Float16 h8v __attribute__((ext_vector_type(8)));
typedef _Float16 h4v __attribute__((ext_vector_type(4)));
typedef float f4v __attribute__((ext_vector_type(4)));

#define NEGF (-3.4028234663852886e38f)

static __device__ __forceinline__ void gload16(const void* g, void* l) {
  __builtin_amdgcn_global_load_lds((const __attribute__((address_space(1))) void*)g,
                                   (__attribute__((address_space(3))) void*)l, 16, 0, 0);
}

// ---------------- cast hidden fp32 -> fp16 ----------------
__global__ __launch_bounds__(256) void cast_hs_kernel(const float* __restrict__ in,
                                                      _Float16* __restrict__ out) {
  int i = (blockIdx.x * 256 + threadIdx.x) * 4;
  float4 v = *(const float4*)(in + i);
  h4v o = {(_Float16)v.x, (_Float16)v.y, (_Float16)v.z, (_Float16)v.w};
  *(h4v*)(out + i) = o;
}

// ---------------- weight transpose+cast: W fp32 [K][N] -> Wt fp16 [N][K] ----------------
__global__ __launch_bounds__(256) void wtrans_kernel(const float* __restrict__ W,
                                                     _Float16* __restrict__ Wt) {
  __shared__ float tile[32][33];
  int tx = threadIdx.x & 31, ty = threadIdx.x >> 5;
  int c0 = blockIdx.x * 32;  // n
  int r0 = blockIdx.y * 32;  // k
  for (int i = 0; i < 4; i++)
    tile[ty + i * 8][tx] = W[(size_t)(r0 + ty + i * 8) * 4096 + c0 + tx];
  __syncthreads();
  for (int i = 0; i < 4; i++)
    Wt[(size_t)(c0 + ty + i * 8) * 4096 + r0 + tx] = (_Float16)tile[tx][ty + i * 8];
}

// ---------------- GEMM: A[1920][4096] fp16  x  Bt[4096(N)][4096(K)] fp16 ----------------
// 128x128 tile, 4 waves (2x2), each wave 64x64 via 4x4 mfma_f32_16x16x32_f16 frags.
// LDS layout [kchunk(4)][row(128)][8]: lane-contiguous per wave -> global_load_lds ok.
template <typename OutT, bool HEAD_LAYOUT>
__global__ __launch_bounds__(256) void gemm_kernel(const _Float16* __restrict__ A,
                                                   const _Float16* __restrict__ Bt,
                                                   OutT* __restrict__ C) {
  const int K = 4096, N = 4096;
  int m0 = blockIdx.y * 128, n0 = blockIdx.x * 128;
  __shared__ __align__(16) _Float16 As[4096];
  __shared__ __align__(16) _Float16 Bs[4096];
  int t = threadIdx.x;
  int lane = t & 63, w = t >> 6, quad = lane >> 4, l16 = lane & 15;
  int wm = (w >> 1) * 64, wn = (w & 1) * 64;
  f4v acc[4][4] = {};
  int c_a = t >> 7;   // k-chunk for slot 0 (0..1); slot 1 handles c+2
  int mr = t & 127;
  const _Float16* Arow0 = A + (size_t)(m0 + mr) * K + c_a * 8;
  const _Float16* Arow1 = Arow0 + 16;
  const _Float16* Brow0 = Bt + (size_t)(n0 + mr) * K + c_a * 8;
  const _Float16* Brow1 = Brow0 + 16;
  for (int kk = 0; kk < K; kk += 32) {
    __syncthreads();
    gload16(Arow0 + kk, As + t * 8);
    gload16(Arow1 + kk, As + (t + 256) * 8);
    gload16(Brow0 + kk, Bs + t * 8);
    gload16(Brow1 + kk, Bs + (t + 256) * 8);
    __syncthreads();
    h8v af[4], bf[4];
    for (int mi = 0; mi < 4; mi++)
      af[mi] = *(const h8v*)(As + (quad * 128 + wm + mi * 16 + l16) * 8);
    for (int ni = 0; ni < 4; ni++)
      bf[ni] = *(const h8v*)(Bs + (quad * 128 + wn + ni * 16 + l16) * 8);
    for (int mi = 0; mi < 4; mi++)
      for (int ni = 0; ni < 4; ni++)
        acc[mi][ni] = __builtin_amdgcn_mfma_f32_16x16x32_f16(af[mi], bf[ni], acc[mi][ni], 0, 0, 0);
  }
  for (int mi = 0; mi < 4; mi++)
    for (int ni = 0; ni < 4; ni++) {
      int col = n0 + wn + ni * 16 + l16;
      for (int rr = 0; rr < 4; rr++) {
        int row = m0 + wm + mi * 16 + quad * 4 + rr;  // D: row=(lane>>4)*4+reg, col=lane&15
        size_t oidx;
        if (HEAD_LAYOUT) {
          int b = row >= 960 ? 1 : 0;
          int q = row - b * 960;
          oidx = ((size_t)(b * 32 + (col >> 7)) * 960 + q) * 128 + (col & 127);
        } else {
          oidx = (size_t)row * N + col;
        }
        C[oidx] = (OutT)acc[mi][ni][rr];
      }
    }
}

// ---------------- in-place RoPE on [bh][q][128] fp16 ----------------
__global__ __launch_bounds__(256) void rope_kernel(_Float16* __restrict__ x) {
  int idx = blockIdx.x * 256 + threadIdx.x;
  int d = idx & 63;
  int rest = idx >> 6;        // bh*960 + q
  int q = rest % 960;
  size_t base = (size_t)rest * 128 + d;
  float x1 = (float)x[base], x2 = (float)x[base + 64];
  float invf = exp2f((float)d * -0.20762050593046016f);  // 10000^(-d/64)
  float ang = (float)q * invf;
  float c = cosf(ang), s = sinf(ang);
  x[base]      = (_Float16)(x1 * c - x2 * s);
  x[base + 64] = (_Float16)(x2 * c + x1 * s);
}

// ---------------- V transpose per head: [bh][q][d] -> [bh][d][q] ----------------
__global__ __launch_bounds__(256) void vtrans_kernel(const _Float16* __restrict__ in,
                                                     _Float16* __restrict__ vt) {
  __shared__ _Float16 tile[32][33];
  int tx = threadIdx.x & 31, ty = threadIdx.x >> 5;
  int q0 = blockIdx.x * 32;
  int d0 = blockIdx.y * 32;
  int bh = blockIdx.z;
  for (int i = 0; i < 4; i++)
    tile[ty + i * 8][tx] = in[((size_t)bh * 960 + q0 + ty + i * 8) * 128 + d0 + tx];
  __syncthreads();
  for (int i = 0; i < 4; i++)
    vt[((size_t)bh * 128 + d0 + ty + i * 8) * 960 + q0 + tx] = tile[tx][ty + i * 8];
}

// ---------------- fused landmark attention ----------------
// grid (60 qtiles, 64 bh), 256 threads. 16 q-rows per block, full-k S row in LDS.
// Groups are 64-column blocks -> one wave per (row, group), shuffle reductions.
__global__ __launch_bounds__(256) void attn_kernel(const _Float16* __restrict__ qr,
                                                   const _Float16* __restrict__ kr,
                                                   const _Float16* __restrict__ vt,
                                                   _Float16* __restrict__ attn_out) {
  const int qt = blockIdx.x;
  const int bh = blockIdx.y;
  const int b = bh >> 5, h = bh & 31;
  const int q0 = qt * 16;
  const int qb = q0 >> 6;     // current 64-block index; landmarks at 64j+63
  const int t = threadIdx.x;
  const int w = t >> 6, lane = t & 63, quad = lane >> 4, l16 = lane & 15;

  // stride 964 == 4 (mod 32): row-major wave access = 2-way bank alias (free)
  __shared__ __align__(16) float S[16][964];
  __shared__ float Mg[16][16];   // group max
  __shared__ float Dg[16][16];   // group denom
  __shared__ float Wg[16][16];   // per-group multiplier: g<qb -> lm_gate/denom; [15] -> 1/D15

  // Q fragments (A-operand: m=lane&15 row, k=quad*8+j)
  const _Float16* qbase = qr + (size_t)(bh * 960 + q0) * 128;
  h8v qf[4];
  for (int dc = 0; dc < 4; dc++)
    qf[dc] = *(const h8v*)(qbase + l16 * 128 + dc * 32 + quad * 8);

  // Phase 1: S[q][k] for k < 64*(qb+1), causal-masked, scaled
  const float rscale = 0.08838834764831845f;  // 1/sqrt(128)
  for (int kt = 0; kt <= qb; kt++) {
    int kc0 = kt * 64 + w * 16;
    const _Float16* kbase = kr + (size_t)(bh * 960 + kc0 + l16) * 128;
    f4v acc = {0.f, 0.f, 0.f, 0.f};
    for (int dc = 0; dc < 4; dc++) {
      h8v kf = *(const h8v*)(kbase + dc * 32 + quad * 8);  // B-op: n=lane&15 (k-col), k=d
      acc = __builtin_amdgcn_mfma_f32_16x16x32_f16(qf[dc], kf, acc, 0, 0, 0);
    }
    int kcol = kc0 + l16;
    for (int r = 0; r < 4; r++) {
      int m = quad * 4 + r;
      S[m][kcol] = (kcol <= q0 + m) ? acc[r] * rscale : NEGF;
    }
  }
  __syncthreads();

  // Phase 2: wave-parallel group max + exp-sum. pair p -> row r=p&15, sub-group gi=p>>4.
  // gi<qb: prior group gi (63 non-mem cols). gi==qb: group 15 (current block + landmarks).
  const int ng = qb + 1;
  for (int p = w; p < 16 * ng; p += 4) {
    int r = p & 15, gi = p >> 4;
    if (gi == qb) {
      float v1 = S[r][qb * 64 + lane];
      float v2 = (lane < qb) ? S[r][lane * 64 + 63] : NEGF;
      float mx = fmaxf(v1, v2);
      for (int m = 32; m; m >>= 1) mx = fmaxf(mx, __shfl_xor(mx, m));
      float e = __expf(v1 - mx) + ((lane < qb) ? __expf(v2 - mx) : 0.f);
      for (int m = 32; m; m >>= 1) e += __shfl_xor(e, m);
      if (lane == 0) { Mg[r][15] = mx; Dg[r][15] = e; }
    } else {
      float v1 = (lane < 63) ? S[r][gi * 64 + lane] : NEGF;
      float mx = v1;
      for (int m = 32; m; m >>= 1) mx = fmaxf(mx, __shfl_xor(mx, m));
      float e = (lane < 63) ? __expf(v1 - mx) : 0.f;
      for (int m = 32; m; m >>= 1) e += __shfl_xor(e, m);
      if (lane == 0) { Mg[r][gi] = mx; Dg[r][gi] = e; }
    }
  }
  __syncthreads();

  // Phase 3: per-group multipliers
  {
    int r = t & 15, g = t >> 4;
    if (g < qb)
      Wg[r][g] = __expf(S[r][g * 64 + 63] - Mg[r][15]) / (Dg[r][15] * Dg[r][g]);
    else if (g == 15)
      Wg[r][15] = 1.f / Dg[r][15];
  }
  __syncthreads();

  // Phase 4: final weights in place, one lane per column
  for (int p = w; p < 16 * ng; p += 4) {
    int r = p & 15, g = p >> 4;
    int k = g * 64 + lane;
    float s = S[r][k];
    float wgt;
    if (g == qb)           wgt = __expf(s - Mg[r][15]) * Wg[r][15];
    else if (lane == 63)   wgt = 0.f;                              // foreign landmark
    else                   wgt = __expf(s - Mg[r][g]) * Wg[r][g];
    S[r][k] = wgt;
  }
  __syncthreads();

  // Phase 5: PV. wave w -> d columns [w*32, w*32+32)
  {
    int d0 = w * 32;
    const _Float16* vbase = vt + (size_t)(bh * 128 + d0) * 960;
    f4v oacc[2] = {{0.f, 0.f, 0.f, 0.f}, {0.f, 0.f, 0.f, 0.f}};
    int nkc = (qb + 1) * 2;
    for (int kc = 0; kc < nkc; kc++) {
      int k0 = kc * 32 + quad * 8;
      float4 wa = *(const float4*)&S[l16][k0];
      float4 wb = *(const float4*)&S[l16][k0 + 4];
      h8v af = {(_Float16)wa.x, (_Float16)wa.y, (_Float16)wa.z, (_Float16)wa.w,
                (_Float16)wb.x, (_Float16)wb.y, (_Float16)wb.z, (_Float16)wb.w};
      for (int nt = 0; nt < 2; nt++) {
        h8v bfv = *(const h8v*)(vbase + (nt * 16 + l16) * 960 + k0);
        oacc[nt] = __builtin_amdgcn_mfma_f32_16x16x32_f16(af, bfv, oacc[nt], 0, 0, 0);
      }
    }
    for (int nt = 0; nt < 2; nt++)
      for (int rr = 0; rr < 4; rr++) {
        int qrow = q0 + quad * 4 + rr;
        int col = h * 128 + d0 + nt * 16 + l16;
        attn_out[(size_t)(b * 960 + qrow) * 4096 + col] = (_Float16)oacc[nt][rr];
      }
  }
}

extern "C" void kernel_launch(void* const* d_in, const int* in_sizes, int n_in,
                              void* d_out, int out_size, void* d_ws, size_t ws_size,
                              hipStream_t stream) {
  (void)in_sizes; (void)n_in; (void)out_size; (void)ws_size;
  const float* hs = (const float*)d_in[0];
  const float* wq = (const float*)d_in[1];
  const float* wk = (const float*)d_in[2];
  const float* wv = (const float*)d_in[3];
  const float* wo = (const float*)d_in[4];
  char* ws = (char*)d_ws;
  _Float16* wt   = (_Float16*)(ws);                 // 33,554,432 B
  _Float16* hsf  = (_Float16*)(ws + 33554432ull);   // 15,728,640 B (also attn_out alias)
  _Float16* qr   = (_Float16*)(ws + 49283072ull);   // 15,728,640 B
  _Float16* kr   = (_Float16*)(ws + 65011712ull);   // 15,728,640 B
  _Float16* vtmp = (_Float16*)(ws + 80740352ull);   // 15,728,640 B
  _Float16* vt   = (_Float16*)(ws + 96468992ull);   // 15,728,640 B  (total 112,197,632 B)
  _Float16* attn = hsf;   // hsf dead after V GEMM
  float* out = (float*)d_out;

  hipLaunchKernelGGL(cast_hs_kernel, dim3(7680), dim3(256), 0, stream, hs, hsf);

  // Q
  hipLaunchKernelGGL(wtrans_kernel, dim3(128, 128), dim3(256), 0, stream, wq, wt);
  hipLaunchKernelGGL((gemm_kernel<_Float16, true>), dim3(32, 15), dim3(256), 0, stream, hsf, wt, qr);
  hipLaunchKernelGGL(rope_kernel, dim3(15360), dim3(256), 0, stream, qr);
  // K
  hipLaunchKernelGGL(wtrans_kernel, dim3(128, 128), dim3(256), 0, stream, wk, wt);
  hipLaunchKernelGGL((gemm_kernel<_Float16, true>), dim3(32, 15), dim3(256), 0, stream, hsf, wt, kr);
  hipLaunchKernelGGL(rope_kernel, dim3(15360), dim3(256), 0, stream, kr);
  // V
  hipLaunchKernelGGL(wtrans_kernel, dim3(128, 128), dim3(256), 0, stream, wv, wt);
  hipLaunchKernelGGL((gemm_kernel<_Float16, true>), dim3(32, 15), dim3(256), 0, stream, hsf, wt, vtmp);
  hipLaunchKernelGGL(vtrans_kernel, dim3(30, 4, 64), dim3(256), 0, stream, vtmp, vt);
  // attention
  hipLaunchKernelGGL(attn_kernel, dim3(60, 64), dim3(256), 0, stream, qr, kr, vt, attn);
  // O
  hipLaunchKernelGGL(wtrans_kernel, dim3(128, 128), dim3(256), 0, stream, wo, wt);
  hipLaunchKernelGGL((gemm_kernel<float, false>), dim3(32, 15), dim3(256), 0, stream, attn, wt, out);
}

// Round 3
// 1125.478 us; speedup vs baseline: 1.0062x; 1.0062x over previous
//
#include <hip/hip_runtime.h>

typedef _Float16 h8v __attribute__((ext_vector_type(8)));
typedef _Float16 h4v __attribute__((ext_vector_type(4)));
typedef float f4v __attribute__((ext_vector_type(4)));

#define NEGF (-3.4028234663852886e38f)

static __device__ __forceinline__ void gload16(const void* g, void* l) {
  __builtin_amdgcn_global_load_lds((const __attribute__((address_space(1))) void*)g,
                                   (__attribute__((address_space(3))) void*)l, 16, 0, 0);
}

// ---------------- cast hidden fp32 -> fp16 ----------------
__global__ __launch_bounds__(256) void cast_hs_kernel(const float* __restrict__ in,
                                                      _Float16* __restrict__ out) {
  int i = (blockIdx.x * 256 + threadIdx.x) * 4;
  float4 v = *(const float4*)(in + i);
  h4v o = {(_Float16)v.x, (_Float16)v.y, (_Float16)v.z, (_Float16)v.w};
  *(h4v*)(out + i) = o;
}

// ---------------- weight transpose+cast: W fp32 [K][N] -> Wt fp16 [N][K] ----------------
__global__ __launch_bounds__(256) void wtrans_kernel(const float* __restrict__ W,
                                                     _Float16* __restrict__ Wt) {
  __shared__ float tile[32][33];
  int tx = threadIdx.x & 31, ty = threadIdx.x >> 5;
  int c0 = blockIdx.x * 32;  // n
  int r0 = blockIdx.y * 32;  // k
  for (int i = 0; i < 4; i++)
    tile[ty + i * 8][tx] = W[(size_t)(r0 + ty + i * 8) * 4096 + c0 + tx];
  __syncthreads();
  for (int i = 0; i < 4; i++)
    Wt[(size_t)(c0 + ty + i * 8) * 4096 + r0 + tx] = (_Float16)tile[tx][ty + i * 8];
}

// ---------------- GEMM mainloop: 128x128 tile, A/Bt both [row][4096k] fp16 ----------------
static __device__ __forceinline__ void gemm_mainloop(const _Float16* __restrict__ A,
                                                     const _Float16* __restrict__ Bt,
                                                     _Float16* As, _Float16* Bs,
                                                     f4v (&acc)[4][4]) {
  const int K = 4096;
  int t = threadIdx.x;
  int lane = t & 63, w = t >> 6, quad = lane >> 4, l16 = lane & 15;
  int wm = (w >> 1) * 64, wn = (w & 1) * 64;
  int c_a = t >> 7, mr = t & 127;
  const _Float16* Arow0 = A + (size_t)mr * K + c_a * 8;
  const _Float16* Arow1 = Arow0 + 16;
  const _Float16* Brow0 = Bt + (size_t)mr * K + c_a * 8;
  const _Float16* Brow1 = Brow0 + 16;
  for (int kk = 0; kk < K; kk += 32) {
    __syncthreads();
    gload16(Arow0 + kk, As + t * 8);
    gload16(Arow1 + kk, As + (t + 256) * 8);
    gload16(Brow0 + kk, Bs + t * 8);
    gload16(Brow1 + kk, Bs + (t + 256) * 8);
    __syncthreads();
    h8v af[4], bf[4];
    for (int mi = 0; mi < 4; mi++)
      af[mi] = *(const h8v*)(As + (quad * 128 + wm + mi * 16 + l16) * 8);
    for (int ni = 0; ni < 4; ni++)
      bf[ni] = *(const h8v*)(Bs + (quad * 128 + wn + ni * 16 + l16) * 8);
    for (int mi = 0; mi < 4; mi++)
      for (int ni = 0; ni < 4; ni++)
        acc[mi][ni] = __builtin_amdgcn_mfma_f32_16x16x32_f16(af[mi], bf[ni], acc[mi][ni], 0, 0, 0);
  }
}

// ---------------- fused QKV GEMM: grid (96, 15); x%3 selects weight ----------------
__global__ __launch_bounds__(256) void gemm_qkv_kernel(const _Float16* __restrict__ A,
                                                       const _Float16* __restrict__ W3,
                                                       _Float16* __restrict__ qr,
                                                       _Float16* __restrict__ kr,
                                                       _Float16* __restrict__ vtmp) {
  __shared__ __align__(16) _Float16 As[4096];
  __shared__ __align__(16) _Float16 Bs[4096];
  int which = blockIdx.x % 3;
  int n0 = (blockIdx.x / 3) * 128;
  int m0 = blockIdx.y * 128;
  const _Float16* Bt = W3 + (size_t)which * 16777216 + (size_t)n0 * 4096;
  _Float16* C = which == 0 ? qr : (which == 1 ? kr : vtmp);
  f4v acc[4][4] = {};
  gemm_mainloop(A + (size_t)m0 * 4096, Bt, As, Bs, acc);
  int t = threadIdx.x, lane = t & 63, w = t >> 6, quad = lane >> 4, l16 = lane & 15;
  int wm = (w >> 1) * 64, wn = (w & 1) * 64;
  for (int mi = 0; mi < 4; mi++)
    for (int ni = 0; ni < 4; ni++) {
      int col = n0 + wn + ni * 16 + l16;
      for (int rr = 0; rr < 4; rr++) {
        int row = m0 + wm + mi * 16 + quad * 4 + rr;
        int bb = row >= 960 ? 1 : 0;
        int q = row - bb * 960;
        C[((size_t)(bb * 32 + (col >> 7)) * 960 + q) * 128 + (col & 127)] = (_Float16)acc[mi][ni][rr];
      }
    }
}

// ---------------- single GEMM, head-layout fp16 out (fallback path) ----------------
__global__ __launch_bounds__(256) void gemm_head_kernel(const _Float16* __restrict__ A,
                                                        const _Float16* __restrict__ Bt,
                                                        _Float16* __restrict__ C) {
  __shared__ __align__(16) _Float16 As[4096];
  __shared__ __align__(16) _Float16 Bs[4096];
  int n0 = blockIdx.x * 128, m0 = blockIdx.y * 128;
  f4v acc[4][4] = {};
  gemm_mainloop(A + (size_t)m0 * 4096, Bt + (size_t)n0 * 4096, As, Bs, acc);
  int t = threadIdx.x, lane = t & 63, w = t >> 6, quad = lane >> 4, l16 = lane & 15;
  int wm = (w >> 1) * 64, wn = (w & 1) * 64;
  for (int mi = 0; mi < 4; mi++)
    for (int ni = 0; ni < 4; ni++) {
      int col = n0 + wn + ni * 16 + l16;
      for (int rr = 0; rr < 4; rr++) {
        int row = m0 + wm + mi * 16 + quad * 4 + rr;
        int bb = row >= 960 ? 1 : 0;
        int q = row - bb * 960;
        C[((size_t)(bb * 32 + (col >> 7)) * 960 + q) * 128 + (col & 127)] = (_Float16)acc[mi][ni][rr];
      }
    }
}

// ---------------- O-projection GEMM, fp32 row-major out ----------------
__global__ __launch_bounds__(256) void gemm_o_kernel(const _Float16* __restrict__ A,
                                                     const _Float16* __restrict__ Bt,
                                                     float* __restrict__ Cout) {
  __shared__ __align__(16) _Float16 As[4096];
  __shared__ __align__(16) _Float16 Bs[4096];
  int n0 = blockIdx.x * 128, m0 = blockIdx.y * 128;
  f4v acc[4][4] = {};
  gemm_mainloop(A + (size_t)m0 * 4096, Bt + (size_t)n0 * 4096, As, Bs, acc);
  int t = threadIdx.x, lane = t & 63, w = t >> 6, quad = lane >> 4, l16 = lane & 15;
  int wm = (w >> 1) * 64, wn = (w & 1) * 64;
  for (int mi = 0; mi < 4; mi++)
    for (int ni = 0; ni < 4; ni++) {
      int col = n0 + wn + ni * 16 + l16;
      for (int rr = 0; rr < 4; rr++) {
        int row = m0 + wm + mi * 16 + quad * 4 + rr;
        Cout[(size_t)row * 4096 + col] = acc[mi][ni][rr];
      }
    }
}

// ---------------- RoPE on qr and kr in one launch ----------------
__global__ __launch_bounds__(256) void rope2_kernel(_Float16* __restrict__ qx,
                                                    _Float16* __restrict__ kx) {
  _Float16* x = blockIdx.y ? kx : qx;
  int idx = blockIdx.x * 256 + threadIdx.x;
  int d = idx & 63;
  int rest = idx >> 6;        // bh*960 + q
  int q = rest % 960;
  size_t base = (size_t)rest * 128 + d;
  float x1 = (float)x[base], x2 = (float)x[base + 64];
  float invf = exp2f((float)d * -0.20762050593046016f);  // 10000^(-d/64)
  float ang = (float)q * invf;
  float c = cosf(ang), s = sinf(ang);
  x[base]      = (_Float16)(x1 * c - x2 * s);
  x[base + 64] = (_Float16)(x2 * c + x1 * s);
}

// ---------------- V transpose per head: [bh][q][d] -> [bh][d][q] ----------------
__global__ __launch_bounds__(256) void vtrans_kernel(const _Float16* __restrict__ in,
                                                     _Float16* __restrict__ vt) {
  __shared__ _Float16 tile[32][33];
  int tx = threadIdx.x & 31, ty = threadIdx.x >> 5;
  int q0 = blockIdx.x * 32;
  int d0 = blockIdx.y * 32;
  int bh = blockIdx.z;
  for (int i = 0; i < 4; i++)
    tile[ty + i * 8][tx] = in[((size_t)bh * 960 + q0 + ty + i * 8) * 128 + d0 + tx];
  __syncthreads();
  for (int i = 0; i < 4; i++)
    vt[((size_t)bh * 128 + d0 + ty + i * 8) * 960 + q0 + tx] = tile[tx][ty + i * 8];
}

// ---------------- flash-style landmark attention ----------------
// grid (15 q-blocks, 64 bh), 4 waves; wave w owns rows q0+w*16..+15, fully independent.
// Pass 1: group stats in registers (lane l16 = group id, butterfly reductions).
// Pass 2: recompute scores, apply closed-form landmark weights, P->LDS->A-frag, PV MFMA.
// No __syncthreads anywhere; LDS = 4 * 16 * 72 * 2B = 9216 B.
__global__ __launch_bounds__(256) void attn_kernel(const _Float16* __restrict__ qr,
                                                   const _Float16* __restrict__ kr,
                                                   const _Float16* __restrict__ vt,
                                                   _Float16* __restrict__ attn_out) {
  const int qt = blockIdx.x;        // 0..14; landmarks at 64j+63
  const int bh = blockIdx.y;
  const int b = bh >> 5, h = bh & 31;
  const int q0 = qt * 64;
  const int t = threadIdx.x;
  const int w = t >> 6, lane = t & 63, quad = lane >> 4, l16 = lane & 15;
  const int lquad = lane & 48;

  __shared__ __align__(16) _Float16 P[4][16][72];

  const float rscale = 0.08838834764831845f;  // 1/sqrt(128)
  const int r0 = q0 + w * 16;

  // Q fragments (A-op: m=l16, k=quad*8+j)
  const _Float16* qptr = qr + (size_t)(bh * 960 + r0 + l16) * 128 + quad * 8;
  h8v qf[4];
  for (int dc = 0; dc < 4; dc++) qf[dc] = *(const h8v*)(qptr + dc * 32);

  float sM[4], sD[4], sL[4], Wmul[4];
  float Mcur[4], Dcur[4], M15[4], iD15[4];

  // ---- pass 1: per-group stats ----
  for (int g = 0; g <= qt; g++) {
    f4v acc[4];
    for (int ct = 0; ct < 4; ct++) {
      const _Float16* kptr = kr + (size_t)(bh * 960 + g * 64 + ct * 16 + l16) * 128 + quad * 8;
      f4v a = {0.f, 0.f, 0.f, 0.f};
      for (int dc = 0; dc < 4; dc++)
        a = __builtin_amdgcn_mfma_f32_16x16x32_f16(qf[dc], *(const h8v*)(kptr + dc * 32), a, 0, 0, 0);
      for (int rr = 0; rr < 4; rr++) acc[ct][rr] = a[rr] * rscale;
    }
    if (g < qt) {
      // group g = 63 non-landmark cols; col 63 (ct==3,l16==15) is the landmark (group 15)
      for (int rr = 0; rr < 4; rr++) {
        float s3 = acc[3][rr];
        float mx = fmaxf(fmaxf(acc[0][rr], acc[1][rr]), acc[2][rr]);
        if (l16 != 15) mx = fmaxf(mx, s3);
        for (int m = 8; m; m >>= 1) mx = fmaxf(mx, __shfl_xor(mx, m));
        float e = __expf(acc[0][rr] - mx) + __expf(acc[1][rr] - mx) + __expf(acc[2][rr] - mx);
        if (l16 != 15) e += __expf(s3 - mx);
        for (int m = 8; m; m >>= 1) e += __shfl_xor(e, m);
        float slm = __shfl(s3, lquad + 15);
        if (l16 == g) { sM[rr] = mx; sD[rr] = e; sL[rr] = slm; }
      }
    } else {
      // current block: causal-masked, includes own landmark; part of group 15
      for (int rr = 0; rr < 4; rr++) {
        int row = r0 + quad * 4 + rr;
        float v0 = (q0 + 0 * 16 + l16 <= row) ? acc[0][rr] : NEGF;
        float v1 = (q0 + 1 * 16 + l16 <= row) ? acc[1][rr] : NEGF;
        float v2 = (q0 + 2 * 16 + l16 <= row) ? acc[2][rr] : NEGF;
        float v3 = (q0 + 3 * 16 + l16 <= row) ? acc[3][rr] : NEGF;
        float mx = fmaxf(fmaxf(v0, v1), fmaxf(v2, v3));
        for (int m = 8; m; m >>= 1) mx = fmaxf(mx, __shfl_xor(mx, m));
        float e = 0.f;
        if (v0 > -1e38f) e += __expf(v0 - mx);
        if (v1 > -1e38f) e += __expf(v1 - mx);
        if (v2 > -1e38f) e += __expf(v2 - mx);
        if (v3 > -1e38f) e += __expf(v3 - mx);
        for (int m = 8; m; m >>= 1) e += __shfl_xor(e, m);
        Mcur[rr] = mx; Dcur[rr] = e;
      }
    }
  }

  // ---- group-15 stats (current block + prior landmarks) + per-group multipliers ----
  for (int rr = 0; rr < 4; rr++) {
    float vlm = (l16 < qt) ? sL[rr] : NEGF;
    float ml = vlm;
    for (int m = 8; m; m >>= 1) ml = fmaxf(ml, __shfl_xor(ml, m));
    float m15 = fmaxf(Mcur[rr], ml);
    float es = (l16 < qt) ? __expf(sL[rr] - m15) : 0.f;
    float sum = es;
    for (int m = 8; m; m >>= 1) sum += __shfl_xor(sum, m);
    float d15 = Dcur[rr] * __expf(Mcur[rr] - m15) + sum;
    M15[rr] = m15;
    iD15[rr] = 1.f / d15;
    Wmul[rr] = es * iD15[rr] / sD[rr];   // valid on lanes l16 < qt
  }

  // ---- pass 2: weights + PV ----
  f4v oacc[8] = {};
  for (int g = 0; g <= qt; g++) {
    f4v acc[4];
    for (int ct = 0; ct < 4; ct++) {
      const _Float16* kptr = kr + (size_t)(bh * 960 + g * 64 + ct * 16 + l16) * 128 + quad * 8;
      f4v a = {0.f, 0.f, 0.f, 0.f};
      for (int dc = 0; dc < 4; dc++)
        a = __builtin_amdgcn_mfma_f32_16x16x32_f16(qf[dc], *(const h8v*)(kptr + dc * 32), a, 0, 0, 0);
      for (int rr = 0; rr < 4; rr++) acc[ct][rr] = a[rr] * rscale;
    }
    float bM[4], bW[4];
    if (g < qt)
      for (int rr = 0; rr < 4; rr++) {
        bM[rr] = __shfl(sM[rr], lquad + g);
        bW[rr] = __shfl(Wmul[rr], lquad + g);
      }
    for (int ct = 0; ct < 4; ct++)
      for (int rr = 0; rr < 4; rr++) {
        float wgt;
        if (g == qt) {
          int col = q0 + ct * 16 + l16;
          int row = r0 + quad * 4 + rr;
          wgt = (col <= row) ? __expf(acc[ct][rr] - M15[rr]) * iD15[rr] : 0.f;
        } else {
          wgt = (ct == 3 && l16 == 15) ? 0.f : __expf(acc[ct][rr] - bM[rr]) * bW[rr];
        }
        P[w][quad * 4 + rr][ct * 16 + l16] = (_Float16)wgt;
      }
    __builtin_amdgcn_wave_barrier();
    for (int c = 0; c < 2; c++) {
      h8v af = *(const h8v*)&P[w][l16][c * 32 + quad * 8];
      const _Float16* vbase = vt + (size_t)bh * 122880 + (size_t)(g * 64 + c * 32 + quad * 8);
      for (int dt = 0; dt < 8; dt++) {
        const _Float16* vptr = vbase + (size_t)(dt * 16 + l16) * 960;
        oacc[dt] = __builtin_amdgcn_mfma_f32_16x16x32_f16(af, *(const h8v*)vptr, oacc[dt], 0, 0, 0);
      }
    }
    __builtin_amdgcn_wave_barrier();
  }

  // ---- epilogue ----
  _Float16* obase = attn_out + (size_t)(b * 960 + r0 + quad * 4) * 4096 + h * 128 + l16;
  for (int dt = 0; dt < 8; dt++)
    for (int rr = 0; rr < 4; rr++)
      obase[(size_t)rr * 4096 + dt * 16] = (_Float16)oacc[dt][rr];
}

extern "C" void kernel_launch(void* const* d_in, const int* in_sizes, int n_in,
                              void* d_out, int out_size, void* d_ws, size_t ws_size,
                              hipStream_t stream) {
  (void)in_sizes; (void)n_in; (void)out_size;
  const float* hs = (const float*)d_in[0];
  const float* wq = (const float*)d_in[1];
  const float* wk = (const float*)d_in[2];
  const float* wv = (const float*)d_in[3];
  const float* wo = (const float*)d_in[4];
  char* ws = (char*)d_ws;
  float* out = (float*)d_out;

  if (ws_size >= 212860928ull) {
    // fused path: all 4 transposed weights live simultaneously
    _Float16* wt3  = (_Float16*)(ws);                  // 3 x 33,554,432 B
    _Float16* wto  = (_Float16*)(ws + 100663296ull);   // 33,554,432
    _Float16* hsf  = (_Float16*)(ws + 134217728ull);   // 15,728,640 (attn_out alias)
    _Float16* qr   = (_Float16*)(ws + 149946368ull);
    _Float16* kr   = (_Float16*)(ws + 165675008ull);
    _Float16* vtmp = (_Float16*)(ws + 181403648ull);
    _Float16* vt   = (_Float16*)(ws + 197132288ull);   // end 212,860,928
    _Float16* attn = hsf;

    hipLaunchKernelGGL(cast_hs_kernel, dim3(7680), dim3(256), 0, stream, hs, hsf);
    hipLaunchKernelGGL(wtrans_kernel, dim3(128, 128), dim3(256), 0, stream, wq, wt3);
    hipLaunchKernelGGL(wtrans_kernel, dim3(128, 128), dim3(256), 0, stream, wk, wt3 + 16777216);
    hipLaunchKernelGGL(wtrans_kernel, dim3(128, 128), dim3(256), 0, stream, wv, wt3 + 33554432);
    hipLaunchKernelGGL(wtrans_kernel, dim3(128, 128), dim3(256), 0, stream, wo, wto);
    hipLaunchKernelGGL(gemm_qkv_kernel, dim3(96, 15), dim3(256), 0, stream, hsf, wt3, qr, kr, vtmp);
    hipLaunchKernelGGL(rope2_kernel, dim3(15360, 2), dim3(256), 0, stream, qr, kr);
    hipLaunchKernelGGL(vtrans_kernel, dim3(30, 4, 64), dim3(256), 0, stream, vtmp, vt);
    hipLaunchKernelGGL(attn_kernel, dim3(15, 64), dim3(256), 0, stream, qr, kr, vt, attn);
    hipLaunchKernelGGL(gemm_o_kernel, dim3(32, 15), dim3(256), 0, stream, attn, wto, out);
  } else {
    // fallback: sequential, single wt buffer (112,197,632 B total)
    _Float16* wt   = (_Float16*)(ws);
    _Float16* hsf  = (_Float16*)(ws + 33554432ull);
    _Float16* qr   = (_Float16*)(ws + 49283072ull);
    _Float16* kr   = (_Float16*)(ws + 65011712ull);
    _Float16* vtmp = (_Float16*)(ws + 80740352ull);
    _Float16* vt   = (_Float16*)(ws + 96468992ull);
    _Float16* attn = hsf;

    hipLaunchKernelGGL(cast_hs_kernel, dim3(7680), dim3(256), 0, stream, hs, hsf);
    hipLaunchKernelGGL(wtrans_kernel, dim3(128, 128), dim3(256), 0, stream, wq, wt);
    hipLaunchKernelGGL(gemm_head_kernel, dim3(32, 15), dim3(256), 0, stream, hsf, wt, qr);
    hipLaunchKernelGGL(wtrans_kernel, dim3(128, 128), dim3(256), 0, stream, wk, wt);
    hipLaunchKernelGGL(gemm_head_kernel, dim3(32, 15), dim3(256), 0, stream, hsf, wt, kr);
    hipLaunchKernelGGL(rope2_kernel, dim3(15360, 2), dim3(256), 0, stream, qr, kr);
    hipLaunchKernelGGL(wtrans_kernel, dim3(128, 128), dim3(256), 0, stream, wv, wt);
    hipLaunchKernelGGL(gemm_head_kernel, dim3(32, 15), dim3(256), 0, stream, hsf, wt, vtmp);
    hipLaunchKernelGGL(vtrans_kernel, dim3(30, 4, 64), dim3(256), 0, stream, vtmp, vt);
    hipLaunchKernelGGL(attn_kernel, dim3(15, 64), dim3(256), 0, stream, qr, kr, vt, attn);
    hipLaunchKernelGGL(wtrans_kernel, dim3(128, 128), dim3(256), 0, stream, wo, wt);
    hipLaunchKernelGGL(gemm_o_kernel, dim3(32, 15), dim3(256), 0, stream, attn, wt, out);
  }
}